// Round 1
// baseline (1830.291 us; speedup 1.0000x reference)
//
#include <hip/hip_runtime.h>
#include <hip/hip_bf16.h>
#include <math.h>

// Problem constants
constexpr int Bc    = 4;
constexpr int DIMc  = 128;
constexpr int Hc    = 48;
constexpr int Wc    = 48;
constexpr int HWc   = Hc * Wc;        // 2304
constexpr int Ltot  = 2 * HWc;        // 4608
constexpr int DIN   = 256;            // d_inner
constexpr int DST   = 16;             // d_state
constexpr int DTR   = 8;              // dt_rank
constexpr int ROWS  = Bc * Ltot;      // 18432

// ---------------------------------------------------------------------------
// K1: LayerNorm over c=128 of cat([pan,ms]) -> x [ROWS,128]
// One wave (64 lanes) per row; 2 channels per lane.
// ---------------------------------------------------------------------------
__global__ __launch_bounds__(256) void ln_cat_k(
    const float* __restrict__ pan, const float* __restrict__ ms,
    const float* __restrict__ lw, const float* __restrict__ lb,
    float* __restrict__ x) {
  int wave = (blockIdx.x * 256 + threadIdx.x) >> 6;   // row 0..ROWS-1
  int lane = threadIdx.x & 63;
  if (wave >= ROWS) return;
  int b = wave / Ltot;
  int l = wave - b * Ltot;
  const float* src = (l < HWc) ? pan : ms;
  int i = (l < HWc) ? l : l - HWc;
  float v0 = src[((size_t)b * DIMc + lane) * HWc + i];
  float v1 = src[((size_t)b * DIMc + lane + 64) * HWc + i];
  float s = v0 + v1, ss = v0 * v0 + v1 * v1;
  #pragma unroll
  for (int m = 1; m < 64; m <<= 1) { s += __shfl_xor(s, m); ss += __shfl_xor(ss, m); }
  float mean = s * (1.f / 128.f);
  float var  = ss * (1.f / 128.f) - mean * mean;
  float rstd = rsqrtf(var + 1e-5f);
  float* xr = x + (size_t)wave * DIMc;
  xr[lane]      = (v0 - mean) * rstd * lw[lane]      + lb[lane];
  xr[lane + 64] = (v1 - mean) * rstd * lw[lane + 64] + lb[lane + 64];
}

// ---------------------------------------------------------------------------
// Generic fp32 GEMM: C[m,n] = sum_k A[m*lda+k] * Bw[n*ldb+k]
// Block 256 threads, tile 64x64, K-step 16, 4x4 per thread.
// M must be a multiple of 64; N guarded.
// ---------------------------------------------------------------------------
__global__ __launch_bounds__(256) void gemm_nt(
    const float* __restrict__ A, int lda,
    const float* __restrict__ Bw, int ldb,
    float* __restrict__ C, int ldc,
    int M, int N, int K) {
  __shared__ float As[16][68];
  __shared__ float Bs[16][68];
  int tid = threadIdx.x;
  int m0 = blockIdx.y * 64;
  int n0 = blockIdx.x * 64;
  int tm = (tid & 15) * 4;
  int tn = (tid >> 4) * 4;
  int lk = tid & 15;      // k within K-tile
  int lr = tid >> 4;      // 0..15
  float acc[4][4] = {};
  for (int k0 = 0; k0 < K; k0 += 16) {
    #pragma unroll
    for (int r = 0; r < 4; ++r) {
      int m = m0 + lr + 16 * r;
      As[lk][lr + 16 * r] = A[(size_t)m * lda + k0 + lk];
    }
    #pragma unroll
    for (int r = 0; r < 4; ++r) {
      int n = n0 + lr + 16 * r;
      Bs[lk][lr + 16 * r] = (n < N) ? Bw[(size_t)n * ldb + k0 + lk] : 0.f;
    }
    __syncthreads();
    #pragma unroll
    for (int k = 0; k < 16; ++k) {
      float a[4], bb[4];
      #pragma unroll
      for (int i = 0; i < 4; ++i) a[i] = As[k][tm + i];
      #pragma unroll
      for (int j = 0; j < 4; ++j) bb[j] = Bs[k][tn + j];
      #pragma unroll
      for (int i = 0; i < 4; ++i)
        #pragma unroll
        for (int j = 0; j < 4; ++j)
          acc[i][j] = fmaf(a[i], bb[j], acc[i][j]);
    }
    __syncthreads();
  }
  #pragma unroll
  for (int i = 0; i < 4; ++i) {
    int m = m0 + tm + i;
    #pragma unroll
    for (int j = 0; j < 4; ++j) {
      int n = n0 + tn + j;
      if (n < N) C[(size_t)m * ldc + n] = acc[i][j];
    }
  }
}

// ---------------------------------------------------------------------------
// K3: causal depthwise conv1d (taps=4) + SiLU.
// xz[row*512 + d] (d<256) is conv input; output xs[row*256+d].
// One block per row (b,l); thread = channel d.
// ---------------------------------------------------------------------------
__global__ __launch_bounds__(256) void conv_silu_k(
    const float* __restrict__ xz, const float* __restrict__ cw,
    const float* __restrict__ cb, float* __restrict__ xs) {
  int row = blockIdx.x;                 // b*Ltot + l
  int d = threadIdx.x;
  int b = row / Ltot;
  int l = row - b * Ltot;
  const float* base = xz + (size_t)b * Ltot * 512 + d;
  float acc = cb[d];
  float w0 = cw[d * 4 + 0], w1 = cw[d * 4 + 1], w2 = cw[d * 4 + 2], w3 = cw[d * 4 + 3];
  if (l >= 3) {
    acc = fmaf(w0, base[(size_t)(l - 3) * 512], acc);
    acc = fmaf(w1, base[(size_t)(l - 2) * 512], acc);
    acc = fmaf(w2, base[(size_t)(l - 1) * 512], acc);
    acc = fmaf(w3, base[(size_t)l * 512], acc);
  } else {
    if (l - 3 >= 0) acc = fmaf(w0, base[(size_t)(l - 3) * 512], acc);
    if (l - 2 >= 0) acc = fmaf(w1, base[(size_t)(l - 2) * 512], acc);
    if (l - 1 >= 0) acc = fmaf(w2, base[(size_t)(l - 1) * 512], acc);
    acc = fmaf(w3, base[(size_t)l * 512], acc);
  }
  float sig = 1.f / (1.f + __expf(-acc));
  xs[(size_t)row * 256 + d] = acc * sig;
}

// ---------------------------------------------------------------------------
// K5: delta = softplus(dt @ dt_W^T + dt_b); dt = dbl[:, 0:8]
// One block per row; thread = channel d.
// ---------------------------------------------------------------------------
__global__ __launch_bounds__(256) void delta_k(
    const float* __restrict__ dbl, const float* __restrict__ dtW,
    const float* __restrict__ dtb, float* __restrict__ dlt) {
  int row = blockIdx.x;
  int d = threadIdx.x;
  const float* dr = dbl + (size_t)row * 40;
  float acc = dtb[d];
  #pragma unroll
  for (int r = 0; r < 8; ++r) acc = fmaf(dr[r], dtW[d * 8 + r], acc);
  float sp = (acc > 20.f) ? acc : log1pf(__expf(acc));
  dlt[(size_t)row * 256 + d] = sp;
}

// ---------------------------------------------------------------------------
// K6: selective scan. 16 lanes per (b,d) channel, one state n per lane.
// h = exp(delta*A)*h + delta*B*xs ; y = sum_n h*C ; fused epilogue with
// skip (xs*D) and gate silu(z). y written into xz cols 0:256 (stride 512).
// ---------------------------------------------------------------------------
__global__ __launch_bounds__(256) void scan_k(
    const float* __restrict__ dlt, const float* __restrict__ xsb,
    const float* __restrict__ dbl, const float* __restrict__ xz,
    const float* __restrict__ A_log, const float* __restrict__ Dp,
    float* __restrict__ y) {
  int tid = threadIdx.x;
  int g = tid >> 4;            // 0..15  (channel within block)
  int n = tid & 15;            // state index
  int bi = blockIdx.x;         // 0..63
  int b = bi >> 4;
  int d = ((bi & 15) << 4) + g;
  float An = -__expf(A_log[d * 16 + n]);
  float Dd = Dp[d];
  size_t rb = (size_t)b * Ltot;
  float h = 0.f;
  // prefetch l=0
  size_t row = rb;
  float dltv = dlt[row * 256 + d];
  float xv   = xsb[row * 256 + d];
  float Bn   = dbl[row * 40 + 8 + n];
  float Cn   = dbl[row * 40 + 24 + n];
  float zv   = xz[row * 512 + 256 + d];
  for (int l = 0; l < Ltot; ++l) {
    float dltc = dltv, xc = xv, Bc_ = Bn, Cc = Cn, zc = zv;
    if (l + 1 < Ltot) {
      size_t r2 = rb + l + 1;
      dltv = dlt[r2 * 256 + d];
      xv   = xsb[r2 * 256 + d];
      Bn   = dbl[r2 * 40 + 8 + n];
      Cn   = dbl[r2 * 40 + 24 + n];
      zv   = xz[r2 * 512 + 256 + d];
    }
    float dA = __expf(dltc * An);
    h = fmaf(dA, h, dltc * Bc_ * xc);
    float p = h * Cc;
    p += __shfl_xor(p, 1); p += __shfl_xor(p, 2);
    p += __shfl_xor(p, 4); p += __shfl_xor(p, 8);
    if (n == 0) {
      float sil = zc / (1.f + __expf(-zc));
      y[(rb + l) * 512 + d] = (p + xc * Dd) * sil;
    }
  }
}

// ---------------------------------------------------------------------------
// K8: out = pan + ms + fused[b,i,:] + fused[b,hw+i,:]  (transposed gather)
// ---------------------------------------------------------------------------
__global__ __launch_bounds__(256) void final_k(
    const float* __restrict__ pan, const float* __restrict__ ms,
    const float* __restrict__ fused, float* __restrict__ out) {
  int idx = blockIdx.x * 256 + threadIdx.x;     // b*128*2304 + c*2304 + i
  int b = idx / (DIMc * HWc);
  int rem = idx - b * DIMc * HWc;
  int c = rem / HWc;
  int i = rem - c * HWc;
  size_t r0 = ((size_t)b * Ltot + i) * DIMc + c;
  size_t r1 = ((size_t)b * Ltot + HWc + i) * DIMc + c;
  out[idx] = pan[idx] + ms[idx] + fused[r0] + fused[r1];
}

// ---------------------------------------------------------------------------
extern "C" void kernel_launch(void* const* d_in, const int* in_sizes, int n_in,
                              void* d_out, int out_size, void* d_ws, size_t ws_size,
                              hipStream_t stream) {
  const float* pan   = (const float*)d_in[0];
  const float* ms    = (const float*)d_in[1];
  const float* ln_w  = (const float*)d_in[2];
  const float* ln_b  = (const float*)d_in[3];
  const float* inW   = (const float*)d_in[4];
  const float* convw = (const float*)d_in[5];
  const float* convb = (const float*)d_in[6];
  const float* xprW  = (const float*)d_in[7];
  const float* dtW   = (const float*)d_in[8];
  const float* dtb   = (const float*)d_in[9];
  const float* A_log = (const float*)d_in[10];
  const float* Dp    = (const float*)d_in[11];
  const float* outW  = (const float*)d_in[12];
  float* out = (float*)d_out;

  float* ws = (float*)d_ws;
  float* x    = ws;                       // [ROWS,128]  (reused as fused)
  float* xz   = x   + (size_t)ROWS * 128; // [ROWS,512]  cols 0:256 xs_raw -> later y
  float* xs   = xz  + (size_t)ROWS * 512; // [ROWS,256]  conv+silu output
  float* dbl  = xs  + (size_t)ROWS * 256; // [ROWS,40]
  float* dlt  = dbl + (size_t)ROWS * 40;  // [ROWS,256]

  // K1: layernorm of cat
  ln_cat_k<<<ROWS / 4, 256, 0, stream>>>(pan, ms, ln_w, ln_b, x);
  // K2: in_proj  x[ROWS,128] @ inW[512,128]^T -> xz[ROWS,512]
  gemm_nt<<<dim3(512 / 64, ROWS / 64), 256, 0, stream>>>(
      x, 128, inW, 128, xz, 512, ROWS, 512, 128);
  // K3: depthwise causal conv + silu -> xs[ROWS,256]
  conv_silu_k<<<ROWS, 256, 0, stream>>>(xz, convw, convb, xs);
  // K4: x_proj  xs[ROWS,256] @ xprW[40,256]^T -> dbl[ROWS,40]
  gemm_nt<<<dim3(1, ROWS / 64), 256, 0, stream>>>(
      xs, 256, xprW, 256, dbl, 40, ROWS, 40, 256);
  // K5: delta = softplus(dt @ dtW^T + dtb) -> dlt[ROWS,256]
  delta_k<<<ROWS, 256, 0, stream>>>(dbl, dtW, dtb, dlt);
  // K6: selective scan -> y into xz cols 0:256 (stride 512)
  scan_k<<<64, 256, 0, stream>>>(dlt, xs, dbl, xz, A_log, Dp, xz);
  // K7: out_proj  y[ROWS,256](lda=512) @ outW[128,256]^T -> fused = x[ROWS,128]
  gemm_nt<<<dim3(2, ROWS / 64), 256, 0, stream>>>(
      xz, 512, outW, 256, x, 128, ROWS, 128, 256);
  // K8: residual + fold p+m, transpose to [b,c,h,w]
  final_k<<<(Bc * DIMc * HWc) / 256, 256, 0, stream>>>(pan, ms, x, out);
}

// Round 2
// 321.829 us; speedup vs baseline: 5.6872x; 5.6872x over previous
//
#include <hip/hip_runtime.h>
#include <hip/hip_bf16.h>
#include <math.h>

// Problem constants
constexpr int Bc    = 4;
constexpr int DIMc  = 128;
constexpr int Hc    = 48;
constexpr int Wc    = 48;
constexpr int HWc   = Hc * Wc;        // 2304
constexpr int Ltot  = 2 * HWc;        // 4608
constexpr int DIN   = 256;            // d_inner
constexpr int DST   = 16;             // d_state
constexpr int DTR   = 8;              // dt_rank
constexpr int ROWS  = Bc * Ltot;      // 18432
constexpr int NCH   = 32;             // scan chunks
constexpr int LCH   = Ltot / NCH;     // 144 steps per chunk
constexpr int LANES = Bc * DIN * DST; // 16384 scan lanes

// ---------------------------------------------------------------------------
// K1: LayerNorm over c=128 of cat([pan,ms]) -> x [ROWS,128]
// ---------------------------------------------------------------------------
__global__ __launch_bounds__(256) void ln_cat_k(
    const float* __restrict__ pan, const float* __restrict__ ms,
    const float* __restrict__ lw, const float* __restrict__ lb,
    float* __restrict__ x) {
  int wave = (blockIdx.x * 256 + threadIdx.x) >> 6;
  int lane = threadIdx.x & 63;
  if (wave >= ROWS) return;
  int b = wave / Ltot;
  int l = wave - b * Ltot;
  const float* src = (l < HWc) ? pan : ms;
  int i = (l < HWc) ? l : l - HWc;
  float v0 = src[((size_t)b * DIMc + lane) * HWc + i];
  float v1 = src[((size_t)b * DIMc + lane + 64) * HWc + i];
  float s = v0 + v1, ss = v0 * v0 + v1 * v1;
  #pragma unroll
  for (int m = 1; m < 64; m <<= 1) { s += __shfl_xor(s, m); ss += __shfl_xor(ss, m); }
  float mean = s * (1.f / 128.f);
  float var  = ss * (1.f / 128.f) - mean * mean;
  float rstd = rsqrtf(var + 1e-5f);
  float* xr = x + (size_t)wave * DIMc;
  xr[lane]      = (v0 - mean) * rstd * lw[lane]      + lb[lane];
  xr[lane + 64] = (v1 - mean) * rstd * lw[lane + 64] + lb[lane + 64];
}

// ---------------------------------------------------------------------------
// Generic fp32 GEMM: C[m,n] = sum_k A[m*lda+k] * Bw[n*ldb+k]
// ---------------------------------------------------------------------------
__global__ __launch_bounds__(256) void gemm_nt(
    const float* __restrict__ A, int lda,
    const float* __restrict__ Bw, int ldb,
    float* __restrict__ C, int ldc,
    int M, int N, int K) {
  __shared__ float As[16][68];
  __shared__ float Bs[16][68];
  int tid = threadIdx.x;
  int m0 = blockIdx.y * 64;
  int n0 = blockIdx.x * 64;
  int tm = (tid & 15) * 4;
  int tn = (tid >> 4) * 4;
  int lk = tid & 15;
  int lr = tid >> 4;
  float acc[4][4] = {};
  for (int k0 = 0; k0 < K; k0 += 16) {
    #pragma unroll
    for (int r = 0; r < 4; ++r) {
      int m = m0 + lr + 16 * r;
      As[lk][lr + 16 * r] = A[(size_t)m * lda + k0 + lk];
    }
    #pragma unroll
    for (int r = 0; r < 4; ++r) {
      int n = n0 + lr + 16 * r;
      Bs[lk][lr + 16 * r] = (n < N) ? Bw[(size_t)n * ldb + k0 + lk] : 0.f;
    }
    __syncthreads();
    #pragma unroll
    for (int k = 0; k < 16; ++k) {
      float a[4], bb[4];
      #pragma unroll
      for (int i = 0; i < 4; ++i) a[i] = As[k][tm + i];
      #pragma unroll
      for (int j = 0; j < 4; ++j) bb[j] = Bs[k][tn + j];
      #pragma unroll
      for (int i = 0; i < 4; ++i)
        #pragma unroll
        for (int j = 0; j < 4; ++j)
          acc[i][j] = fmaf(a[i], bb[j], acc[i][j]);
    }
    __syncthreads();
  }
  #pragma unroll
  for (int i = 0; i < 4; ++i) {
    int m = m0 + tm + i;
    #pragma unroll
    for (int j = 0; j < 4; ++j) {
      int n = n0 + tn + j;
      if (n < N) C[(size_t)m * ldc + n] = acc[i][j];
    }
  }
}

// ---------------------------------------------------------------------------
// K3: causal depthwise conv1d (taps=4) + SiLU.
// ---------------------------------------------------------------------------
__global__ __launch_bounds__(256) void conv_silu_k(
    const float* __restrict__ xz, const float* __restrict__ cw,
    const float* __restrict__ cb, float* __restrict__ xs) {
  int row = blockIdx.x;
  int d = threadIdx.x;
  int b = row / Ltot;
  int l = row - b * Ltot;
  const float* base = xz + (size_t)b * Ltot * 512 + d;
  float acc = cb[d];
  float w0 = cw[d * 4 + 0], w1 = cw[d * 4 + 1], w2 = cw[d * 4 + 2], w3 = cw[d * 4 + 3];
  if (l >= 3) {
    acc = fmaf(w0, base[(size_t)(l - 3) * 512], acc);
    acc = fmaf(w1, base[(size_t)(l - 2) * 512], acc);
    acc = fmaf(w2, base[(size_t)(l - 1) * 512], acc);
    acc = fmaf(w3, base[(size_t)l * 512], acc);
  } else {
    if (l - 3 >= 0) acc = fmaf(w0, base[(size_t)(l - 3) * 512], acc);
    if (l - 2 >= 0) acc = fmaf(w1, base[(size_t)(l - 2) * 512], acc);
    if (l - 1 >= 0) acc = fmaf(w2, base[(size_t)(l - 1) * 512], acc);
    acc = fmaf(w3, base[(size_t)l * 512], acc);
  }
  float sig = 1.f / (1.f + __expf(-acc));
  xs[(size_t)row * 256 + d] = acc * sig;
}

// ---------------------------------------------------------------------------
// K5: delta = softplus(dt @ dt_W^T + dt_b)
// ---------------------------------------------------------------------------
__global__ __launch_bounds__(256) void delta_k(
    const float* __restrict__ dbl, const float* __restrict__ dtW,
    const float* __restrict__ dtb, float* __restrict__ dlt) {
  int row = blockIdx.x;
  int d = threadIdx.x;
  const float* dr = dbl + (size_t)row * 40;
  float acc = dtb[d];
  #pragma unroll
  for (int r = 0; r < 8; ++r) acc = fmaf(dr[r], dtW[d * 8 + r], acc);
  float sp = (acc > 20.f) ? acc : log1pf(__expf(acc));
  dlt[(size_t)row * 256 + d] = sp;
}

// ---------------------------------------------------------------------------
// Chunk-parallel selective scan.
// Lane layout per block: 256 threads = 16 channels (g) x 16 states (n).
// Block id: blk = c*64 + b*16 + dg ; d = dg*16 + g.
// Buffers P,S,Hin: idx = c*LANES + b*4096 + d*16 + n (contig 256 per block).
// ---------------------------------------------------------------------------
__global__ __launch_bounds__(256) void scan_p1(
    const float* __restrict__ dlt, const float* __restrict__ xsb,
    const float* __restrict__ dbl, const float* __restrict__ A_log,
    float* __restrict__ Pb, float* __restrict__ Sb) {
  int tid = threadIdx.x;
  int g = tid >> 4, n = tid & 15;
  int blk = blockIdx.x;
  int c = blk >> 6;
  int r = blk & 63;
  int b = r >> 4, dg = r & 15;
  int d = dg * 16 + g;
  float An = -__expf(A_log[d * 16 + n]);
  size_t rb = (size_t)b * Ltot + (size_t)c * LCH;
  float h = 0.f, P = 1.f;
  float dltv = dlt[rb * 256 + d];
  float xv   = xsb[rb * 256 + d];
  float Bn   = dbl[rb * 40 + 8 + n];
  for (int l = 0; l < LCH; ++l) {
    float dltc = dltv, xc = xv, Bv = Bn;
    if (l + 1 < LCH) {
      size_t r2 = rb + l + 1;
      dltv = dlt[r2 * 256 + d];
      xv   = xsb[r2 * 256 + d];
      Bn   = dbl[r2 * 40 + 8 + n];
    }
    float a = __expf(dltc * An);
    h = fmaf(a, h, dltc * Bv * xc);
    P *= a;
  }
  size_t idx = (size_t)c * LANES + (size_t)b * 4096 + d * 16 + n;
  Pb[idx] = P;
  Sb[idx] = h;
}

__global__ __launch_bounds__(256) void scan_p2(
    const float* __restrict__ Pb, const float* __restrict__ Sb,
    float* __restrict__ Hin) {
  int off = blockIdx.x * 256 + threadIdx.x;   // b*4096 + d*16 + n
  float h = 0.f;
  float Pv = Pb[off], Sv = Sb[off];
  for (int c = 0; c < NCH; ++c) {
    float Pc = Pv, Sc = Sv;
    if (c + 1 < NCH) {
      size_t i2 = (size_t)(c + 1) * LANES + off;
      Pv = Pb[i2];
      Sv = Sb[i2];
    }
    Hin[(size_t)c * LANES + off] = h;
    h = fmaf(Pc, h, Sc);
  }
}

__global__ __launch_bounds__(256) void scan_p3(
    const float* __restrict__ dlt, const float* __restrict__ xsb,
    const float* __restrict__ dbl, const float* __restrict__ xz,
    const float* __restrict__ A_log, const float* __restrict__ Dp,
    const float* __restrict__ Hin, float* __restrict__ y) {
  int tid = threadIdx.x;
  int g = tid >> 4, n = tid & 15;
  int blk = blockIdx.x;
  int c = blk >> 6;
  int r = blk & 63;
  int b = r >> 4, dg = r & 15;
  int d = dg * 16 + g;
  float An = -__expf(A_log[d * 16 + n]);
  float Dd = Dp[d];
  size_t rb = (size_t)b * Ltot + (size_t)c * LCH;
  float h = Hin[(size_t)c * LANES + (size_t)b * 4096 + d * 16 + n];
  float dltv = dlt[rb * 256 + d];
  float xv   = xsb[rb * 256 + d];
  float Bn   = dbl[rb * 40 + 8 + n];
  float Cn   = dbl[rb * 40 + 24 + n];
  float zv   = xz[rb * 512 + 256 + d];
  for (int l = 0; l < LCH; ++l) {
    float dltc = dltv, xc = xv, Bv = Bn, Cv = Cn, zc = zv;
    if (l + 1 < LCH) {
      size_t r2 = rb + l + 1;
      dltv = dlt[r2 * 256 + d];
      xv   = xsb[r2 * 256 + d];
      Bn   = dbl[r2 * 40 + 8 + n];
      Cn   = dbl[r2 * 40 + 24 + n];
      zv   = xz[r2 * 512 + 256 + d];
    }
    float a = __expf(dltc * An);
    h = fmaf(a, h, dltc * Bv * xc);
    float p = h * Cv;
    p += __shfl_xor(p, 1); p += __shfl_xor(p, 2);
    p += __shfl_xor(p, 4); p += __shfl_xor(p, 8);
    if (n == 0) {
      float sil = zc / (1.f + __expf(-zc));
      y[(rb + l) * 512 + d] = (p + xc * Dd) * sil;
    }
  }
}

// ---------------------------------------------------------------------------
// K8: out = pan + ms + fused[b,i,:] + fused[b,hw+i,:]
// ---------------------------------------------------------------------------
__global__ __launch_bounds__(256) void final_k(
    const float* __restrict__ pan, const float* __restrict__ ms,
    const float* __restrict__ fused, float* __restrict__ out) {
  int idx = blockIdx.x * 256 + threadIdx.x;
  int b = idx / (DIMc * HWc);
  int rem = idx - b * DIMc * HWc;
  int c = rem / HWc;
  int i = rem - c * HWc;
  size_t r0 = ((size_t)b * Ltot + i) * DIMc + c;
  size_t r1 = ((size_t)b * Ltot + HWc + i) * DIMc + c;
  out[idx] = pan[idx] + ms[idx] + fused[r0] + fused[r1];
}

// ---------------------------------------------------------------------------
extern "C" void kernel_launch(void* const* d_in, const int* in_sizes, int n_in,
                              void* d_out, int out_size, void* d_ws, size_t ws_size,
                              hipStream_t stream) {
  const float* pan   = (const float*)d_in[0];
  const float* ms    = (const float*)d_in[1];
  const float* ln_w  = (const float*)d_in[2];
  const float* ln_b  = (const float*)d_in[3];
  const float* inW   = (const float*)d_in[4];
  const float* convw = (const float*)d_in[5];
  const float* convb = (const float*)d_in[6];
  const float* xprW  = (const float*)d_in[7];
  const float* dtW   = (const float*)d_in[8];
  const float* dtb   = (const float*)d_in[9];
  const float* A_log = (const float*)d_in[10];
  const float* Dp    = (const float*)d_in[11];
  const float* outW  = (const float*)d_in[12];
  float* out = (float*)d_out;

  float* ws = (float*)d_ws;
  float* x    = ws;                       // [ROWS,128] ; scan P/S/Hin overlay; later fused
  float* xz   = x   + (size_t)ROWS * 128; // [ROWS,512]  cols 0:256 xs_raw -> later y
  float* xs   = xz  + (size_t)ROWS * 512; // [ROWS,256]
  float* dbl  = xs  + (size_t)ROWS * 256; // [ROWS,40]
  float* dlt  = dbl + (size_t)ROWS * 40;  // [ROWS,256]
  // scan summaries overlay x (x is dead between K2 and K7): 3 x 2MB <= 9.4MB
  float* Pb   = x;
  float* Sb   = Pb + (size_t)LANES * NCH;
  float* Hin  = Sb + (size_t)LANES * NCH;

  // K1: layernorm of cat
  ln_cat_k<<<ROWS / 4, 256, 0, stream>>>(pan, ms, ln_w, ln_b, x);
  // K2: in_proj  x[ROWS,128] @ inW[512,128]^T -> xz[ROWS,512]
  gemm_nt<<<dim3(512 / 64, ROWS / 64), 256, 0, stream>>>(
      x, 128, inW, 128, xz, 512, ROWS, 512, 128);
  // K3: depthwise causal conv + silu -> xs[ROWS,256]
  conv_silu_k<<<ROWS, 256, 0, stream>>>(xz, convw, convb, xs);
  // K4: x_proj  xs[ROWS,256] @ xprW[40,256]^T -> dbl[ROWS,40]
  gemm_nt<<<dim3(1, ROWS / 64), 256, 0, stream>>>(
      xs, 256, xprW, 256, dbl, 40, ROWS, 40, 256);
  // K5: delta -> dlt[ROWS,256]
  delta_k<<<ROWS, 256, 0, stream>>>(dbl, dtW, dtb, dlt);
  // K6: chunk-parallel scan -> y into xz cols 0:256 (stride 512)
  scan_p1<<<64 * NCH, 256, 0, stream>>>(dlt, xs, dbl, A_log, Pb, Sb);
  scan_p2<<<64, 256, 0, stream>>>(Pb, Sb, Hin);
  scan_p3<<<64 * NCH, 256, 0, stream>>>(dlt, xs, dbl, xz, A_log, Dp, Hin, xz);
  // K7: out_proj  y[ROWS,256](lda=512) @ outW[128,256]^T -> fused = x[ROWS,128]
  gemm_nt<<<dim3(2, ROWS / 64), 256, 0, stream>>>(
      xz, 512, outW, 256, x, 128, ROWS, 128, 256);
  // K8: residual + fold p+m, transpose to [b,c,h,w]
  final_k<<<(Bc * DIMc * HWc) / 256, 256, 0, stream>>>(pan, ms, x, out);
}

// Round 3
// 246.108 us; speedup vs baseline: 7.4369x; 1.3077x over previous
//
#include <hip/hip_runtime.h>
#include <hip/hip_bf16.h>
#include <math.h>

// Problem constants
constexpr int Bc    = 4;
constexpr int DIMc  = 128;
constexpr int Hc    = 48;
constexpr int Wc    = 48;
constexpr int HWc   = Hc * Wc;        // 2304
constexpr int Ltot  = 2 * HWc;        // 4608
constexpr int DIN   = 256;            // d_inner
constexpr int DST   = 16;             // d_state
constexpr int DTR   = 8;              // dt_rank
constexpr int ROWS  = Bc * Ltot;      // 18432
constexpr int LANES = Bc * DIN * DST; // 16384 scan states

constexpr float LOG2E = 1.4426950408889634f;
constexpr float LN2   = 0.6931471805599453f;

// fast transcendental helpers (native single-instruction forms)
__device__ __forceinline__ float exp2_f(float x) {
#if __has_builtin(__builtin_amdgcn_exp2f)
  return __builtin_amdgcn_exp2f(x);
#else
  float r; asm("v_exp_f32 %0, %1" : "=v"(r) : "v"(x)); return r;
#endif
}
__device__ __forceinline__ float rcp_f(float x) {
#if __has_builtin(__builtin_amdgcn_rcpf)
  return __builtin_amdgcn_rcpf(x);
#else
  float r; asm("v_rcp_f32 %0, %1" : "=v"(r) : "v"(x)); return r;
#endif
}
__device__ __forceinline__ float log2_f(float x) {
#if __has_builtin(__builtin_amdgcn_logf)
  return __builtin_amdgcn_logf(x);
#else
  float r; asm("v_log_f32 %0, %1" : "=v"(r) : "v"(x)); return r;
#endif
}

#define F4C(v, i) ((i) == 0 ? (v).x : (i) == 1 ? (v).y : (i) == 2 ? (v).z : (v).w)

// ---------------------------------------------------------------------------
// K1: LayerNorm over c=128 of cat([pan,ms]) -> x [ROWS,128]
// ---------------------------------------------------------------------------
__global__ __launch_bounds__(256) void ln_cat_k(
    const float* __restrict__ pan, const float* __restrict__ ms,
    const float* __restrict__ lw, const float* __restrict__ lb,
    float* __restrict__ x) {
  int wave = (blockIdx.x * 256 + threadIdx.x) >> 6;
  int lane = threadIdx.x & 63;
  if (wave >= ROWS) return;
  int b = wave / Ltot;
  int l = wave - b * Ltot;
  const float* src = (l < HWc) ? pan : ms;
  int i = (l < HWc) ? l : l - HWc;
  float v0 = src[((size_t)b * DIMc + lane) * HWc + i];
  float v1 = src[((size_t)b * DIMc + lane + 64) * HWc + i];
  float s = v0 + v1, ss = v0 * v0 + v1 * v1;
  #pragma unroll
  for (int m = 1; m < 64; m <<= 1) { s += __shfl_xor(s, m); ss += __shfl_xor(ss, m); }
  float mean = s * (1.f / 128.f);
  float var  = ss * (1.f / 128.f) - mean * mean;
  float rstd = rsqrtf(var + 1e-5f);
  float* xr = x + (size_t)wave * DIMc;
  xr[lane]      = (v0 - mean) * rstd * lw[lane]      + lb[lane];
  xr[lane + 64] = (v1 - mean) * rstd * lw[lane + 64] + lb[lane + 64];
}

// ---------------------------------------------------------------------------
// Generic fp32 GEMM: C[m,n] = sum_k A[m*lda+k] * Bw[n*ldb+k]
// ---------------------------------------------------------------------------
__global__ __launch_bounds__(256) void gemm_nt(
    const float* __restrict__ A, int lda,
    const float* __restrict__ Bw, int ldb,
    float* __restrict__ C, int ldc,
    int M, int N, int K) {
  __shared__ float As[16][68];
  __shared__ float Bs[16][68];
  int tid = threadIdx.x;
  int m0 = blockIdx.y * 64;
  int n0 = blockIdx.x * 64;
  int tm = (tid & 15) * 4;
  int tn = (tid >> 4) * 4;
  int lk = tid & 15;
  int lr = tid >> 4;
  float acc[4][4] = {};
  for (int k0 = 0; k0 < K; k0 += 16) {
    #pragma unroll
    for (int r = 0; r < 4; ++r) {
      int m = m0 + lr + 16 * r;
      As[lk][lr + 16 * r] = A[(size_t)m * lda + k0 + lk];
    }
    #pragma unroll
    for (int r = 0; r < 4; ++r) {
      int n = n0 + lr + 16 * r;
      Bs[lk][lr + 16 * r] = (n < N) ? Bw[(size_t)n * ldb + k0 + lk] : 0.f;
    }
    __syncthreads();
    #pragma unroll
    for (int k = 0; k < 16; ++k) {
      float a[4], bb[4];
      #pragma unroll
      for (int i = 0; i < 4; ++i) a[i] = As[k][tm + i];
      #pragma unroll
      for (int j = 0; j < 4; ++j) bb[j] = Bs[k][tn + j];
      #pragma unroll
      for (int i = 0; i < 4; ++i)
        #pragma unroll
        for (int j = 0; j < 4; ++j)
          acc[i][j] = fmaf(a[i], bb[j], acc[i][j]);
    }
    __syncthreads();
  }
  #pragma unroll
  for (int i = 0; i < 4; ++i) {
    int m = m0 + tm + i;
    #pragma unroll
    for (int j = 0; j < 4; ++j) {
      int n = n0 + tn + j;
      if (n < N) C[(size_t)m * ldc + n] = acc[i][j];
    }
  }
}

// ---------------------------------------------------------------------------
// K3: causal depthwise conv1d (taps=4) + SiLU.
// ---------------------------------------------------------------------------
__global__ __launch_bounds__(256) void conv_silu_k(
    const float* __restrict__ xz, const float* __restrict__ cw,
    const float* __restrict__ cb, float* __restrict__ xs) {
  int row = blockIdx.x;
  int d = threadIdx.x;
  int b = row / Ltot;
  int l = row - b * Ltot;
  const float* base = xz + (size_t)b * Ltot * 512 + d;
  float acc = cb[d];
  float w0 = cw[d * 4 + 0], w1 = cw[d * 4 + 1], w2 = cw[d * 4 + 2], w3 = cw[d * 4 + 3];
  if (l >= 3) {
    acc = fmaf(w0, base[(size_t)(l - 3) * 512], acc);
    acc = fmaf(w1, base[(size_t)(l - 2) * 512], acc);
    acc = fmaf(w2, base[(size_t)(l - 1) * 512], acc);
    acc = fmaf(w3, base[(size_t)l * 512], acc);
  } else {
    if (l - 3 >= 0) acc = fmaf(w0, base[(size_t)(l - 3) * 512], acc);
    if (l - 2 >= 0) acc = fmaf(w1, base[(size_t)(l - 2) * 512], acc);
    if (l - 1 >= 0) acc = fmaf(w2, base[(size_t)(l - 1) * 512], acc);
    acc = fmaf(w3, base[(size_t)l * 512], acc);
  }
  float sig = rcp_f(1.f + exp2_f(-acc * LOG2E));
  xs[(size_t)row * 256 + d] = acc * sig;
}

// ---------------------------------------------------------------------------
// K5: delta = softplus(dt @ dt_W^T + dt_b)
// ---------------------------------------------------------------------------
__global__ __launch_bounds__(256) void delta_k(
    const float* __restrict__ dbl, const float* __restrict__ dtW,
    const float* __restrict__ dtb, float* __restrict__ dlt) {
  int row = blockIdx.x;
  int d = threadIdx.x;
  const float* dr = dbl + (size_t)row * 40;
  float acc = dtb[d];
  #pragma unroll
  for (int r = 0; r < 8; ++r) acc = fmaf(dr[r], dtW[d * 8 + r], acc);
  float e = exp2_f(acc * LOG2E);
  float sp = (acc > 20.f) ? acc : log2_f(1.f + e) * LN2;
  dlt[(size_t)row * 256 + d] = sp;
}

// ---------------------------------------------------------------------------
// Chunk-parallel selective scan, layout B: 1 lane = 1 channel d, 16 states
// in registers. Block = 256 threads = all 256 d for one (b, chunk).
// B/C staged in LDS per chunk (broadcast ds_read_b128).
// Pb/Sb layout: [c][b*4096 + d*16 + n]; p2 turns Pb into Hin in place.
// ---------------------------------------------------------------------------
template <int NCH_>
__global__ __launch_bounds__(256, 2) void scan_p1_k(
    const float* __restrict__ dlt, const float* __restrict__ xsb,
    const float* __restrict__ dbl, const float* __restrict__ A_log,
    float* __restrict__ Pb, float* __restrict__ Sb) {
  constexpr int LCH_ = Ltot / NCH_;
  __shared__ float4 BCs[LCH_ * 8];     // [l][8]: 0..3 = B[16], 4..7 = C[16]
  int tid = threadIdx.x;
  int c = blockIdx.x, b = blockIdx.y;
  size_t rb = (size_t)b * Ltot + (size_t)c * LCH_;
  float* BCf = (float*)BCs;
  for (int i = tid; i < LCH_ * 32; i += 256) {
    int l = i >> 5, j = i & 31;
    BCf[i] = dbl[(rb + l) * 40 + 8 + j];
  }
  __syncthreads();
  int d = tid;
  const float4* Ap = (const float4*)(A_log + d * 16);
  float An2[16];
  #pragma unroll
  for (int k = 0; k < 4; ++k) {
    float4 a4 = Ap[k];
    An2[4 * k + 0] = -exp2_f(a4.x * LOG2E) * LOG2E;
    An2[4 * k + 1] = -exp2_f(a4.y * LOG2E) * LOG2E;
    An2[4 * k + 2] = -exp2_f(a4.z * LOG2E) * LOG2E;
    An2[4 * k + 3] = -exp2_f(a4.w * LOG2E) * LOG2E;
  }
  float h[16];
  #pragma unroll
  for (int n = 0; n < 16; ++n) h[n] = 0.f;
  float sdlt = 0.f;
  const float* dp = dlt + rb * 256 + d;
  const float* xp = xsb + rb * 256 + d;
  for (int ss = 0; ss < LCH_ / 4; ++ss) {
    float dv[4], xv[4];
    #pragma unroll
    for (int u = 0; u < 4; ++u) { dv[u] = dp[u * 256]; xv[u] = xp[u * 256]; }
    #pragma unroll
    for (int u = 0; u < 4; ++u) {
      int l = ss * 4 + u;
      float dl = dv[u];
      sdlt += dl;
      float q = dl * xv[u];
      const float4* row = &BCs[l * 8];
      float4 B4[4] = {row[0], row[1], row[2], row[3]};
      #pragma unroll
      for (int n = 0; n < 16; ++n) {
        float a = exp2_f(dl * An2[n]);
        h[n] = fmaf(a, h[n], q * F4C(B4[n >> 2], n & 3));
      }
    }
    dp += 1024; xp += 1024;
  }
  size_t s0 = ((size_t)b * 256 + d) * 16;
  float4* Pp = (float4*)(Pb + (size_t)c * LANES + s0);
  float4* Sp = (float4*)(Sb + (size_t)c * LANES + s0);
  #pragma unroll
  for (int k = 0; k < 4; ++k) {
    float4 Pq, Sq;
    Pq.x = exp2_f(An2[4 * k + 0] * sdlt);
    Pq.y = exp2_f(An2[4 * k + 1] * sdlt);
    Pq.z = exp2_f(An2[4 * k + 2] * sdlt);
    Pq.w = exp2_f(An2[4 * k + 3] * sdlt);
    Sq.x = h[4 * k + 0]; Sq.y = h[4 * k + 1];
    Sq.z = h[4 * k + 2]; Sq.w = h[4 * k + 3];
    Pp[k] = Pq; Sp[k] = Sq;
  }
}

template <int NCH_>
__global__ __launch_bounds__(256) void scan_p2_k(
    float* __restrict__ Pb, const float* __restrict__ Sb) {
  int s = blockIdx.x * 256 + threadIdx.x;
  float h = 0.f;
  float Pv = Pb[s], Sv = Sb[s];
  for (int c = 0; c < NCH_; ++c) {
    float Pc = Pv, Sc = Sv;
    if (c + 1 < NCH_) {
      Pv = Pb[(size_t)(c + 1) * LANES + s];
      Sv = Sb[(size_t)(c + 1) * LANES + s];
    }
    Pb[(size_t)c * LANES + s] = h;   // Hin, in place (Pb[c] already consumed)
    h = fmaf(Pc, h, Sc);
  }
}

template <int NCH_>
__global__ __launch_bounds__(256, 2) void scan_p3_k(
    const float* __restrict__ dlt, const float* __restrict__ xsb,
    const float* __restrict__ dbl, const float* __restrict__ A_log,
    const float* __restrict__ Dp, const float* __restrict__ Hin,
    const float* __restrict__ zbuf, float* __restrict__ y) {
  constexpr int LCH_ = Ltot / NCH_;
  __shared__ float4 BCs[LCH_ * 8];
  int tid = threadIdx.x;
  int c = blockIdx.x, b = blockIdx.y;
  size_t rb = (size_t)b * Ltot + (size_t)c * LCH_;
  float* BCf = (float*)BCs;
  for (int i = tid; i < LCH_ * 32; i += 256) {
    int l = i >> 5, j = i & 31;
    BCf[i] = dbl[(rb + l) * 40 + 8 + j];
  }
  __syncthreads();
  int d = tid;
  const float4* Ap = (const float4*)(A_log + d * 16);
  float An2[16];
  #pragma unroll
  for (int k = 0; k < 4; ++k) {
    float4 a4 = Ap[k];
    An2[4 * k + 0] = -exp2_f(a4.x * LOG2E) * LOG2E;
    An2[4 * k + 1] = -exp2_f(a4.y * LOG2E) * LOG2E;
    An2[4 * k + 2] = -exp2_f(a4.z * LOG2E) * LOG2E;
    An2[4 * k + 3] = -exp2_f(a4.w * LOG2E) * LOG2E;
  }
  float Dd = Dp[d];
  size_t s0 = ((size_t)b * 256 + d) * 16;
  const float4* Hp = (const float4*)(Hin + (size_t)c * LANES + s0);
  float h[16];
  #pragma unroll
  for (int k = 0; k < 4; ++k) {
    float4 h4 = Hp[k];
    h[4 * k + 0] = h4.x; h[4 * k + 1] = h4.y;
    h[4 * k + 2] = h4.z; h[4 * k + 3] = h4.w;
  }
  const float* dp = dlt + rb * 256 + d;
  const float* xp = xsb + rb * 256 + d;
  const float* zp = zbuf + rb * 512 + 256 + d;
  float* yp = y + rb * 512 + d;
  for (int ss = 0; ss < LCH_ / 4; ++ss) {
    float dv[4], xv[4], zv[4];
    #pragma unroll
    for (int u = 0; u < 4; ++u) {
      dv[u] = dp[u * 256]; xv[u] = xp[u * 256]; zv[u] = zp[u * 512];
    }
    #pragma unroll
    for (int u = 0; u < 4; ++u) {
      int l = ss * 4 + u;
      float dl = dv[u];
      float q = dl * xv[u];
      const float4* row = &BCs[l * 8];
      float4 B4[4] = {row[0], row[1], row[2], row[3]};
      float4 C4[4] = {row[4], row[5], row[6], row[7]};
      float p0 = 0.f, p1 = 0.f, p2 = 0.f, p3 = 0.f;
      #pragma unroll
      for (int n = 0; n < 16; ++n) {
        float a = exp2_f(dl * An2[n]);
        h[n] = fmaf(a, h[n], q * F4C(B4[n >> 2], n & 3));
        float cc = F4C(C4[n >> 2], n & 3);
        if ((n & 3) == 0)      p0 = fmaf(h[n], cc, p0);
        else if ((n & 3) == 1) p1 = fmaf(h[n], cc, p1);
        else if ((n & 3) == 2) p2 = fmaf(h[n], cc, p2);
        else                   p3 = fmaf(h[n], cc, p3);
      }
      float p = (p0 + p1) + (p2 + p3);
      float zc = zv[u];
      float sig = rcp_f(1.f + exp2_f(-zc * LOG2E));
      yp[u * 512] = fmaf(xv[u], Dd, p) * (zc * sig);
    }
    dp += 1024; xp += 1024; zp += 2048; yp += 2048;
  }
}

// ---------------------------------------------------------------------------
// K8: out = pan + ms + fused[b,i,:] + fused[b,hw+i,:]
// ---------------------------------------------------------------------------
__global__ __launch_bounds__(256) void final_k(
    const float* __restrict__ pan, const float* __restrict__ ms,
    const float* __restrict__ fused, float* __restrict__ out) {
  int idx = blockIdx.x * 256 + threadIdx.x;
  int b = idx / (DIMc * HWc);
  int rem = idx - b * DIMc * HWc;
  int c = rem / HWc;
  int i = rem - c * HWc;
  size_t r0 = ((size_t)b * Ltot + i) * DIMc + c;
  size_t r1 = ((size_t)b * Ltot + HWc + i) * DIMc + c;
  out[idx] = pan[idx] + ms[idx] + fused[r0] + fused[r1];
}

// ---------------------------------------------------------------------------
extern "C" void kernel_launch(void* const* d_in, const int* in_sizes, int n_in,
                              void* d_out, int out_size, void* d_ws, size_t ws_size,
                              hipStream_t stream) {
  const float* pan   = (const float*)d_in[0];
  const float* ms    = (const float*)d_in[1];
  const float* ln_w  = (const float*)d_in[2];
  const float* ln_b  = (const float*)d_in[3];
  const float* inW   = (const float*)d_in[4];
  const float* convw = (const float*)d_in[5];
  const float* convb = (const float*)d_in[6];
  const float* xprW  = (const float*)d_in[7];
  const float* dtW   = (const float*)d_in[8];
  const float* dtb   = (const float*)d_in[9];
  const float* A_log = (const float*)d_in[10];
  const float* Dp    = (const float*)d_in[11];
  const float* outW  = (const float*)d_in[12];
  float* out = (float*)d_out;

  float* ws = (float*)d_ws;
  float* x    = ws;                       // [ROWS,128]; dead during scan; later fused
  float* xz   = x   + (size_t)ROWS * 128; // [ROWS,512] cols 0:256 xs_raw -> later y
  float* xs   = xz  + (size_t)ROWS * 512; // [ROWS,256]
  float* dbl  = xs  + (size_t)ROWS * 256; // [ROWS,40]
  float* dlt  = dbl + (size_t)ROWS * 40;  // [ROWS,256]
  float* endp = dlt + (size_t)ROWS * 256; // = ws + 21,970,944 floats

  // K1: layernorm of cat
  ln_cat_k<<<ROWS / 4, 256, 0, stream>>>(pan, ms, ln_w, ln_b, x);
  // K2: in_proj
  gemm_nt<<<dim3(512 / 64, ROWS / 64), 256, 0, stream>>>(
      x, 128, inW, 128, xz, 512, ROWS, 512, 128);
  // K3: conv + silu
  conv_silu_k<<<ROWS, 256, 0, stream>>>(xz, convw, convb, xs);
  // K4: x_proj
  gemm_nt<<<dim3(1, ROWS / 64), 256, 0, stream>>>(
      xs, 256, xprW, 256, dbl, 40, ROWS, 40, 256);
  // K5: delta
  delta_k<<<ROWS, 256, 0, stream>>>(dbl, dtW, dtb, dlt);

  // K6: chunk-parallel scan (layout B). Prefer NCH=192 if workspace allows;
  // fallback NCH=64 with P/S overlaid on the dead x buffer.
  bool big = ws_size >= (size_t)(21970944ull + 2ull * 192 * LANES) * 4ull;
  if (big) {
    constexpr int NC = 192;
    float* Pb = endp;
    float* Sb = endp + (size_t)NC * LANES;
    scan_p1_k<NC><<<dim3(NC, Bc), 256, 0, stream>>>(dlt, xs, dbl, A_log, Pb, Sb);
    scan_p2_k<NC><<<LANES / 256, 256, 0, stream>>>(Pb, Sb);
    scan_p3_k<NC><<<dim3(NC, Bc), 256, 0, stream>>>(dlt, xs, dbl, A_log, Dp, Pb, xz, xz);
  } else {
    constexpr int NC = 64;
    float* Pb = x;
    float* Sb = x + (size_t)NC * LANES;
    scan_p1_k<NC><<<dim3(NC, Bc), 256, 0, stream>>>(dlt, xs, dbl, A_log, Pb, Sb);
    scan_p2_k<NC><<<LANES / 256, 256, 0, stream>>>(Pb, Sb);
    scan_p3_k<NC><<<dim3(NC, Bc), 256, 0, stream>>>(dlt, xs, dbl, A_log, Dp, Pb, xz, xz);
  }

  // K7: out_proj
  gemm_nt<<<dim3(2, ROWS / 64), 256, 0, stream>>>(
      xz, 512, outW, 256, x, 128, ROWS, 128, 256);
  // K8: residual + fold p+m
  final_k<<<(Bc * DIMc * HWc) / 256, 256, 0, stream>>>(pan, ms, x, out);
}

// Round 4
// 175.892 us; speedup vs baseline: 10.4057x; 1.3992x over previous
//
#include <hip/hip_runtime.h>
#include <hip/hip_bf16.h>
#include <math.h>

// Problem constants
constexpr int Bc    = 4;
constexpr int DIMc  = 128;
constexpr int Hc    = 48;
constexpr int Wc    = 48;
constexpr int HWc   = Hc * Wc;        // 2304
constexpr int Ltot  = 2 * HWc;        // 4608
constexpr int DIN   = 256;            // d_inner
constexpr int DST   = 16;             // d_state
constexpr int DTR   = 8;              // dt_rank
constexpr int ROWS  = Bc * Ltot;      // 18432
constexpr int LANES = Bc * DIN * DST; // 16384 scan states

constexpr float LOG2E = 1.4426950408889634f;
constexpr float LN2   = 0.6931471805599453f;

using short8  = __attribute__((ext_vector_type(8))) short;
using float4v = __attribute__((ext_vector_type(4))) float;

// fast transcendental helpers
__device__ __forceinline__ float exp2_f(float x) {
#if __has_builtin(__builtin_amdgcn_exp2f)
  return __builtin_amdgcn_exp2f(x);
#else
  float r; asm("v_exp_f32 %0, %1" : "=v"(r) : "v"(x)); return r;
#endif
}
__device__ __forceinline__ float rcp_f(float x) {
#if __has_builtin(__builtin_amdgcn_rcpf)
  return __builtin_amdgcn_rcpf(x);
#else
  float r; asm("v_rcp_f32 %0, %1" : "=v"(r) : "v"(x)); return r;
#endif
}
__device__ __forceinline__ float log2_f(float x) {
#if __has_builtin(__builtin_amdgcn_logf)
  return __builtin_amdgcn_logf(x);
#else
  float r; asm("v_log_f32 %0, %1" : "=v"(r) : "v"(x)); return r;
#endif
}

#define F4C(v, i) ((i) == 0 ? (v).x : (i) == 1 ? (v).y : (i) == 2 ? (v).z : (v).w)

// ---------------------------------------------------------------------------
// K0a: convert inW + zero-padded xprW to bf16 (into dead dlt region)
// ---------------------------------------------------------------------------
__global__ __launch_bounds__(256) void cvt_w1_k(
    const float* __restrict__ inW, const float* __restrict__ xprW,
    __hip_bfloat16* __restrict__ wb) {
  int i = blockIdx.x * 256 + threadIdx.x;          // 0..65535
  wb[i] = __float2bfloat16(inW[i]);
  if (i < 48 * 256) {
    int n = i >> 8, k = i & 255;
    wb[65536 + i] = __float2bfloat16(n < 40 ? xprW[n * 256 + k] : 0.f);
  }
}
// K6d: convert outW to bf16 (dlt region is dead after scan_p3)
__global__ __launch_bounds__(256) void cvt_w2_k(
    const float* __restrict__ outW, __hip_bfloat16* __restrict__ wb) {
  int i = blockIdx.x * 256 + threadIdx.x;          // 0..32767
  wb[i] = __float2bfloat16(outW[i]);
}

// ---------------------------------------------------------------------------
// K1: LayerNorm over c=128 of cat([pan,ms]) -> xb bf16 [ROWS,128]
// ---------------------------------------------------------------------------
__global__ __launch_bounds__(256) void ln_cat_k(
    const float* __restrict__ pan, const float* __restrict__ ms,
    const float* __restrict__ lw, const float* __restrict__ lb,
    __hip_bfloat16* __restrict__ x) {
  int wave = (blockIdx.x * 256 + threadIdx.x) >> 6;
  int lane = threadIdx.x & 63;
  if (wave >= ROWS) return;
  int b = wave / Ltot;
  int l = wave - b * Ltot;
  const float* src = (l < HWc) ? pan : ms;
  int i = (l < HWc) ? l : l - HWc;
  float v0 = src[((size_t)b * DIMc + lane) * HWc + i];
  float v1 = src[((size_t)b * DIMc + lane + 64) * HWc + i];
  float s = v0 + v1, ss = v0 * v0 + v1 * v1;
  #pragma unroll
  for (int m = 1; m < 64; m <<= 1) { s += __shfl_xor(s, m); ss += __shfl_xor(ss, m); }
  float mean = s * (1.f / 128.f);
  float var  = ss * (1.f / 128.f) - mean * mean;
  float rstd = rsqrtf(var + 1e-5f);
  __hip_bfloat16* xr = x + (size_t)wave * DIMc;
  xr[lane]      = __float2bfloat16((v0 - mean) * rstd * lw[lane]      + lb[lane]);
  xr[lane + 64] = __float2bfloat16((v1 - mean) * rstd * lw[lane + 64] + lb[lane + 64]);
}

// ---------------------------------------------------------------------------
// bf16 MFMA GEMM, no LDS: C[m,n] = sum_k A[m*lda+k] * Bw[n*ldb+k]
// A bf16 [M][lda], Bw bf16 [Npad][ldb]. Block = 4 waves, tile 128 x NF*16.
// Per wave: 32 x NF*16 (2 m-frags x NF n-frags), mfma_f32_16x16x32_bf16.
// A-frag: lane holds A[m0 + (l&15)][k0 + (l>>4)*8 + e]  (16B contiguous).
// B-frag: lane holds Bw[n0 + (l&15)][k0 + (l>>4)*8 + e] (16B contiguous).
// D: col = lane&15, row = (lane>>4)*4 + reg   [m89/m91 verified]
// ---------------------------------------------------------------------------
template <int NF, int KK, int NSTORE>
__global__ __launch_bounds__(256) void gemm_mfma_k(
    const __hip_bfloat16* __restrict__ A, int lda,
    const __hip_bfloat16* __restrict__ Bw, int ldb,
    float* __restrict__ C, int ldc) {
  int lane = threadIdx.x & 63;
  int wv   = threadIdx.x >> 6;
  int m0 = blockIdx.x * 128 + wv * 32;
  int n0 = blockIdx.y * (NF * 16);
  int lm = lane & 15;
  int kb = lane >> 4;
  const short* Ap = (const short*)A + (size_t)(m0 + lm) * lda + kb * 8;
  const short* Bp = (const short*)Bw + (size_t)(n0 + lm) * ldb + kb * 8;
  float4v acc[2][NF] = {};
  for (int k0 = 0; k0 < KK; k0 += 32) {
    short8 a0 = *(const short8*)(Ap);
    short8 a1 = *(const short8*)(Ap + (size_t)16 * lda);
    short8 bfr[NF];
    #pragma unroll
    for (int j = 0; j < NF; ++j) bfr[j] = *(const short8*)(Bp + (size_t)j * 16 * ldb);
    #pragma unroll
    for (int j = 0; j < NF; ++j) {
      acc[0][j] = __builtin_amdgcn_mfma_f32_16x16x32_bf16(a0, bfr[j], acc[0][j], 0, 0, 0);
      acc[1][j] = __builtin_amdgcn_mfma_f32_16x16x32_bf16(a1, bfr[j], acc[1][j], 0, 0, 0);
    }
    Ap += 32; Bp += 32;
  }
  #pragma unroll
  for (int mf = 0; mf < 2; ++mf) {
    #pragma unroll
    for (int j = 0; j < NF; ++j) {
      int col = n0 + j * 16 + lm;
      bool ok = (NSTORE == 0) || (col < NSTORE);
      if (ok) {
        #pragma unroll
        for (int r = 0; r < 4; ++r) {
          int row = m0 + mf * 16 + kb * 4 + r;
          C[(size_t)row * ldc + col] = acc[mf][j][r];
        }
      }
    }
  }
}

// ---------------------------------------------------------------------------
// K3: causal depthwise conv1d (taps=4) + SiLU -> xs fp32 + xsb bf16
// ---------------------------------------------------------------------------
__global__ __launch_bounds__(256) void conv_silu_k(
    const float* __restrict__ xz, const float* __restrict__ cw,
    const float* __restrict__ cb, float* __restrict__ xs,
    __hip_bfloat16* __restrict__ xsb) {
  int row = blockIdx.x;
  int d = threadIdx.x;
  int b = row / Ltot;
  int l = row - b * Ltot;
  const float* base = xz + (size_t)b * Ltot * 512 + d;
  float acc = cb[d];
  float w0 = cw[d * 4 + 0], w1 = cw[d * 4 + 1], w2 = cw[d * 4 + 2], w3 = cw[d * 4 + 3];
  if (l >= 3) {
    acc = fmaf(w0, base[(size_t)(l - 3) * 512], acc);
    acc = fmaf(w1, base[(size_t)(l - 2) * 512], acc);
    acc = fmaf(w2, base[(size_t)(l - 1) * 512], acc);
    acc = fmaf(w3, base[(size_t)l * 512], acc);
  } else {
    if (l - 3 >= 0) acc = fmaf(w0, base[(size_t)(l - 3) * 512], acc);
    if (l - 2 >= 0) acc = fmaf(w1, base[(size_t)(l - 2) * 512], acc);
    if (l - 1 >= 0) acc = fmaf(w2, base[(size_t)(l - 1) * 512], acc);
    acc = fmaf(w3, base[(size_t)l * 512], acc);
  }
  float sig = rcp_f(1.f + exp2_f(-acc * LOG2E));
  float v = acc * sig;
  xs[(size_t)row * 256 + d] = v;
  xsb[(size_t)row * 256 + d] = __float2bfloat16(v);
}

// ---------------------------------------------------------------------------
// K5: delta = softplus(dt @ dt_W^T + dt_b)
// ---------------------------------------------------------------------------
__global__ __launch_bounds__(256) void delta_k(
    const float* __restrict__ dbl, const float* __restrict__ dtW,
    const float* __restrict__ dtb, float* __restrict__ dlt) {
  int row = blockIdx.x;
  int d = threadIdx.x;
  const float* dr = dbl + (size_t)row * 40;
  float acc = dtb[d];
  #pragma unroll
  for (int r = 0; r < 8; ++r) acc = fmaf(dr[r], dtW[d * 8 + r], acc);
  float e = exp2_f(acc * LOG2E);
  float sp = (acc > 20.f) ? acc : log2_f(1.f + e) * LN2;
  dlt[(size_t)row * 256 + d] = sp;
}

// ---------------------------------------------------------------------------
// Chunk-parallel selective scan, layout B (1 lane = 1 channel, 16 states).
// ---------------------------------------------------------------------------
template <int NCH_>
__global__ __launch_bounds__(256, 2) void scan_p1_k(
    const float* __restrict__ dlt, const float* __restrict__ xsb,
    const float* __restrict__ dbl, const float* __restrict__ A_log,
    float* __restrict__ Pb, float* __restrict__ Sb) {
  constexpr int LCH_ = Ltot / NCH_;
  __shared__ float4 BCs[LCH_ * 8];
  int tid = threadIdx.x;
  int c = blockIdx.x, b = blockIdx.y;
  size_t rb = (size_t)b * Ltot + (size_t)c * LCH_;
  float* BCf = (float*)BCs;
  for (int i = tid; i < LCH_ * 32; i += 256) {
    int l = i >> 5, j = i & 31;
    BCf[i] = dbl[(rb + l) * 40 + 8 + j];
  }
  __syncthreads();
  int d = tid;
  const float4* Ap = (const float4*)(A_log + d * 16);
  float An2[16];
  #pragma unroll
  for (int k = 0; k < 4; ++k) {
    float4 a4 = Ap[k];
    An2[4 * k + 0] = -exp2_f(a4.x * LOG2E) * LOG2E;
    An2[4 * k + 1] = -exp2_f(a4.y * LOG2E) * LOG2E;
    An2[4 * k + 2] = -exp2_f(a4.z * LOG2E) * LOG2E;
    An2[4 * k + 3] = -exp2_f(a4.w * LOG2E) * LOG2E;
  }
  float h[16];
  #pragma unroll
  for (int n = 0; n < 16; ++n) h[n] = 0.f;
  float sdlt = 0.f;
  const float* dp = dlt + rb * 256 + d;
  const float* xp = xsb + rb * 256 + d;
  for (int ss = 0; ss < LCH_ / 4; ++ss) {
    float dv[4], xv[4];
    #pragma unroll
    for (int u = 0; u < 4; ++u) { dv[u] = dp[u * 256]; xv[u] = xp[u * 256]; }
    #pragma unroll
    for (int u = 0; u < 4; ++u) {
      int l = ss * 4 + u;
      float dl = dv[u];
      sdlt += dl;
      float q = dl * xv[u];
      const float4* row = &BCs[l * 8];
      float4 B4[4] = {row[0], row[1], row[2], row[3]};
      #pragma unroll
      for (int n = 0; n < 16; ++n) {
        float a = exp2_f(dl * An2[n]);
        h[n] = fmaf(a, h[n], q * F4C(B4[n >> 2], n & 3));
      }
    }
    dp += 1024; xp += 1024;
  }
  size_t s0 = ((size_t)b * 256 + d) * 16;
  float4* Pp = (float4*)(Pb + (size_t)c * LANES + s0);
  float4* Sp = (float4*)(Sb + (size_t)c * LANES + s0);
  #pragma unroll
  for (int k = 0; k < 4; ++k) {
    float4 Pq, Sq;
    Pq.x = exp2_f(An2[4 * k + 0] * sdlt);
    Pq.y = exp2_f(An2[4 * k + 1] * sdlt);
    Pq.z = exp2_f(An2[4 * k + 2] * sdlt);
    Pq.w = exp2_f(An2[4 * k + 3] * sdlt);
    Sq.x = h[4 * k + 0]; Sq.y = h[4 * k + 1];
    Sq.z = h[4 * k + 2]; Sq.w = h[4 * k + 3];
    Pp[k] = Pq; Sp[k] = Sq;
  }
}

template <int NCH_>
__global__ __launch_bounds__(256) void scan_p2_k(
    float* __restrict__ Pb, const float* __restrict__ Sb) {
  int s = blockIdx.x * 256 + threadIdx.x;
  float h = 0.f;
  float Pv = Pb[s], Sv = Sb[s];
  for (int c = 0; c < NCH_; ++c) {
    float Pc = Pv, Sc = Sv;
    if (c + 1 < NCH_) {
      Pv = Pb[(size_t)(c + 1) * LANES + s];
      Sv = Sb[(size_t)(c + 1) * LANES + s];
    }
    Pb[(size_t)c * LANES + s] = h;
    h = fmaf(Pc, h, Sc);
  }
}

template <int NCH_>
__global__ __launch_bounds__(256, 2) void scan_p3_k(
    const float* __restrict__ dlt, const float* __restrict__ xsb,
    const float* __restrict__ dbl, const float* __restrict__ A_log,
    const float* __restrict__ Dp, const float* __restrict__ Hin,
    float* __restrict__ zbuf) {
  constexpr int LCH_ = Ltot / NCH_;
  __shared__ float4 BCs[LCH_ * 8];
  int tid = threadIdx.x;
  int c = blockIdx.x, b = blockIdx.y;
  size_t rb = (size_t)b * Ltot + (size_t)c * LCH_;
  float* BCf = (float*)BCs;
  for (int i = tid; i < LCH_ * 32; i += 256) {
    int l = i >> 5, j = i & 31;
    BCf[i] = dbl[(rb + l) * 40 + 8 + j];
  }
  __syncthreads();
  int d = tid;
  const float4* Ap = (const float4*)(A_log + d * 16);
  float An2[16];
  #pragma unroll
  for (int k = 0; k < 4; ++k) {
    float4 a4 = Ap[k];
    An2[4 * k + 0] = -exp2_f(a4.x * LOG2E) * LOG2E;
    An2[4 * k + 1] = -exp2_f(a4.y * LOG2E) * LOG2E;
    An2[4 * k + 2] = -exp2_f(a4.z * LOG2E) * LOG2E;
    An2[4 * k + 3] = -exp2_f(a4.w * LOG2E) * LOG2E;
  }
  float Dd = Dp[d];
  size_t s0 = ((size_t)b * 256 + d) * 16;
  const float4* Hp = (const float4*)(Hin + (size_t)c * LANES + s0);
  float h[16];
  #pragma unroll
  for (int k = 0; k < 4; ++k) {
    float4 h4 = Hp[k];
    h[4 * k + 0] = h4.x; h[4 * k + 1] = h4.y;
    h[4 * k + 2] = h4.z; h[4 * k + 3] = h4.w;
  }
  const float* dp = dlt + rb * 256 + d;
  const float* xp = xsb + rb * 256 + d;
  const float* zp = zbuf + rb * 512 + 256 + d;
  __hip_bfloat16* yp = (__hip_bfloat16*)zbuf + rb * 1024 + d;  // y bf16 in xz cols 0:128(f32)
  for (int ss = 0; ss < LCH_ / 4; ++ss) {
    float dv[4], xv[4], zv[4];
    #pragma unroll
    for (int u = 0; u < 4; ++u) {
      dv[u] = dp[u * 256]; xv[u] = xp[u * 256]; zv[u] = zp[u * 512];
    }
    #pragma unroll
    for (int u = 0; u < 4; ++u) {
      int l = ss * 4 + u;
      float dl = dv[u];
      float q = dl * xv[u];
      const float4* row = &BCs[l * 8];
      float4 B4[4] = {row[0], row[1], row[2], row[3]};
      float4 C4[4] = {row[4], row[5], row[6], row[7]};
      float p0 = 0.f, p1 = 0.f, p2 = 0.f, p3 = 0.f;
      #pragma unroll
      for (int n = 0; n < 16; ++n) {
        float a = exp2_f(dl * An2[n]);
        h[n] = fmaf(a, h[n], q * F4C(B4[n >> 2], n & 3));
        float cc = F4C(C4[n >> 2], n & 3);
        if ((n & 3) == 0)      p0 = fmaf(h[n], cc, p0);
        else if ((n & 3) == 1) p1 = fmaf(h[n], cc, p1);
        else if ((n & 3) == 2) p2 = fmaf(h[n], cc, p2);
        else                   p3 = fmaf(h[n], cc, p3);
      }
      float p = (p0 + p1) + (p2 + p3);
      float zc = zv[u];
      float sig = rcp_f(1.f + exp2_f(-zc * LOG2E));
      yp[u * 1024] = __float2bfloat16(fmaf(xv[u], Dd, p) * (zc * sig));
    }
    dp += 1024; xp += 1024; zp += 2048; yp += 4096;
  }
}

// ---------------------------------------------------------------------------
// K8: out = pan + ms + fused[b,i,:] + fused[b,hw+i,:]
// ---------------------------------------------------------------------------
__global__ __launch_bounds__(256) void final_k(
    const float* __restrict__ pan, const float* __restrict__ ms,
    const float* __restrict__ fused, float* __restrict__ out) {
  int idx = blockIdx.x * 256 + threadIdx.x;
  int b = idx / (DIMc * HWc);
  int rem = idx - b * DIMc * HWc;
  int c = rem / HWc;
  int i = rem - c * HWc;
  size_t r0 = ((size_t)b * Ltot + i) * DIMc + c;
  size_t r1 = ((size_t)b * Ltot + HWc + i) * DIMc + c;
  out[idx] = pan[idx] + ms[idx] + fused[r0] + fused[r1];
}

// ---------------------------------------------------------------------------
extern "C" void kernel_launch(void* const* d_in, const int* in_sizes, int n_in,
                              void* d_out, int out_size, void* d_ws, size_t ws_size,
                              hipStream_t stream) {
  const float* pan   = (const float*)d_in[0];
  const float* ms    = (const float*)d_in[1];
  const float* ln_w  = (const float*)d_in[2];
  const float* ln_b  = (const float*)d_in[3];
  const float* inW   = (const float*)d_in[4];
  const float* convw = (const float*)d_in[5];
  const float* convb = (const float*)d_in[6];
  const float* xprW  = (const float*)d_in[7];
  const float* dtW   = (const float*)d_in[8];
  const float* dtb   = (const float*)d_in[9];
  const float* A_log = (const float*)d_in[10];
  const float* Dp    = (const float*)d_in[11];
  const float* outW  = (const float*)d_in[12];
  float* out = (float*)d_out;

  float* ws = (float*)d_ws;
  // x region [ROWS*128 f32]: xb(bf16) -> xsb16(bf16) -> [fallback P/S] -> fused(f32)
  float* x    = ws;
  float* xz   = x   + (size_t)ROWS * 128; // [ROWS,512] f32; cols0:256 xs_raw -> later y bf16
  float* xs   = xz  + (size_t)ROWS * 512; // [ROWS,256] f32
  float* dbl  = xs  + (size_t)ROWS * 256; // [ROWS,40]  f32
  float* dlt  = dbl + (size_t)ROWS * 40;  // [ROWS,256] f32; head doubles as bf16 weights
  float* endp = dlt + (size_t)ROWS * 256;

  __hip_bfloat16* xb     = (__hip_bfloat16*)x;
  __hip_bfloat16* xsb16  = (__hip_bfloat16*)x;
  __hip_bfloat16* wb     = (__hip_bfloat16*)dlt;      // inW_b / xprW_b / (later) outW_b
  __hip_bfloat16* inW_b  = wb;
  __hip_bfloat16* xprW_b = wb + 65536;
  __hip_bfloat16* fused  = nullptr; // = x (f32) after out_proj

  // K0: weight conversion (dlt region dead until delta_k)
  cvt_w1_k<<<256, 256, 0, stream>>>(inW, xprW, wb);
  // K1: layernorm -> bf16
  ln_cat_k<<<ROWS / 4, 256, 0, stream>>>(pan, ms, ln_w, ln_b, xb);
  // K2: in_proj MFMA: [ROWS,128]bf16 x [512,128]bf16 -> xz f32 [ROWS,512]
  gemm_mfma_k<4, 128, 0><<<dim3(ROWS / 128, 8), 256, 0, stream>>>(
      xb, 128, inW_b, 128, xz, 512);
  // K3: conv + silu -> xs f32 + xsb16 bf16 (overwrites xb, dead)
  conv_silu_k<<<ROWS, 256, 0, stream>>>(xz, convw, convb, xs, xsb16);
  // K4: x_proj MFMA: [ROWS,256]bf16 x [48,256]bf16 -> dbl f32 [ROWS,40] (guard n<40)
  gemm_mfma_k<3, 256, 40><<<dim3(ROWS / 128, 1), 256, 0, stream>>>(
      xsb16, 256, xprW_b, 256, dbl, 40);
  // K5: delta (overwrites wb region — inW_b/xprW_b dead)
  delta_k<<<ROWS, 256, 0, stream>>>(dbl, dtW, dtb, dlt);

  // K6: chunk-parallel scan
  bool big = ws_size >= (size_t)(21970944ull + 2ull * 192 * LANES) * 4ull;
  if (big) {
    constexpr int NC = 192;
    float* Pb = endp;
    float* Sb = endp + (size_t)NC * LANES;
    scan_p1_k<NC><<<dim3(NC, Bc), 256, 0, stream>>>(dlt, xs, dbl, A_log, Pb, Sb);
    scan_p2_k<NC><<<LANES / 256, 256, 0, stream>>>(Pb, Sb);
    scan_p3_k<NC><<<dim3(NC, Bc), 256, 0, stream>>>(dlt, xs, dbl, A_log, Dp, Pb, xz);
  } else {
    constexpr int NC = 64;
    float* Pb = x;                       // xsb16 dead after K4
    float* Sb = x + (size_t)NC * LANES;
    scan_p1_k<NC><<<dim3(NC, Bc), 256, 0, stream>>>(dlt, xs, dbl, A_log, Pb, Sb);
    scan_p2_k<NC><<<LANES / 256, 256, 0, stream>>>(Pb, Sb);
    scan_p3_k<NC><<<dim3(NC, Bc), 256, 0, stream>>>(dlt, xs, dbl, A_log, Dp, Pb, xz);
  }

  // K6d: outW -> bf16 (dlt dead after p3)
  cvt_w2_k<<<128, 256, 0, stream>>>(outW, wb);
  // K7: out_proj MFMA: y bf16 (in xz, lda=1024) x [128,256]bf16 -> fused f32 (x region)
  gemm_mfma_k<4, 256, 0><<<dim3(ROWS / 128, 2), 256, 0, stream>>>(
      (const __hip_bfloat16*)xz, 1024, wb, 256, x, 128);
  // K8: residual + fold p+m
  final_k<<<(Bc * DIMc * HWc) / 256, 256, 0, stream>>>(pan, ms, x, out);
}

// Round 5
// 131.874 us; speedup vs baseline: 13.8791x; 1.3338x over previous
//
#include <hip/hip_runtime.h>
#include <hip/hip_bf16.h>
#include <math.h>

// Problem constants
constexpr int Bc    = 4;
constexpr int DIMc  = 128;
constexpr int Hc    = 48;
constexpr int Wc    = 48;
constexpr int HWc   = Hc * Wc;        // 2304
constexpr int Ltot  = 2 * HWc;        // 4608
constexpr int DIN   = 256;            // d_inner
constexpr int DST   = 16;             // d_state
constexpr int DTR   = 8;              // dt_rank
constexpr int ROWS  = Bc * Ltot;      // 18432
constexpr int LANES = Bc * DIN * DST; // 16384 scan states
constexpr int NC    = 128;            // scan chunks (LCH=36)

constexpr float LOG2E = 1.4426950408889634f;
constexpr float LN2   = 0.6931471805599453f;

using short8  = __attribute__((ext_vector_type(8))) short;
using float4v = __attribute__((ext_vector_type(4))) float;

__device__ __forceinline__ float exp2_f(float x) {
#if __has_builtin(__builtin_amdgcn_exp2f)
  return __builtin_amdgcn_exp2f(x);
#else
  float r; asm("v_exp_f32 %0, %1" : "=v"(r) : "v"(x)); return r;
#endif
}
__device__ __forceinline__ float rcp_f(float x) {
#if __has_builtin(__builtin_amdgcn_rcpf)
  return __builtin_amdgcn_rcpf(x);
#else
  float r; asm("v_rcp_f32 %0, %1" : "=v"(r) : "v"(x)); return r;
#endif
}
__device__ __forceinline__ float log2_f(float x) {
#if __has_builtin(__builtin_amdgcn_logf)
  return __builtin_amdgcn_logf(x);
#else
  float r; asm("v_log_f32 %0, %1" : "=v"(r) : "v"(x)); return r;
#endif
}

#define F4C(v, i) ((i) == 0 ? (v).x : (i) == 1 ? (v).y : (i) == 2 ? (v).z : (v).w)

// ---------------------------------------------------------------------------
// K0: weight prep. wts layout (bf16): Wq[256][256] | BCw[32][256] |
// inWb[512][128] | outWb[128][256].  Wq[d,k] = sum_r dtW[d,r]*xprW[r,k].
// ---------------------------------------------------------------------------
__global__ __launch_bounds__(256) void prep_w_k(
    const float* __restrict__ inW, const float* __restrict__ xprW,
    const float* __restrict__ dtW, const float* __restrict__ outW,
    __hip_bfloat16* __restrict__ wts) {
  int g = blockIdx.x * 256 + threadIdx.x;
  if (g < 65536) {
    int dd = g >> 8, k = g & 255;
    float acc = 0.f;
    #pragma unroll
    for (int r = 0; r < 8; ++r) acc = fmaf(dtW[dd * 8 + r], xprW[r * 256 + k], acc);
    wts[g] = __float2bfloat16(acc);
  } else if (g < 73728) {
    wts[g] = __float2bfloat16(xprW[2048 + (g - 65536)]);   // rows 8..39 (B,C)
  } else if (g < 139264) {
    wts[g] = __float2bfloat16(inW[g - 73728]);
  } else if (g < 172032) {
    wts[g] = __float2bfloat16(outW[g - 139264]);
  }
}

// ---------------------------------------------------------------------------
// K1: LayerNorm of cat([pan,ms]) -> xb bf16 [ROWS,128].  Coalesced both ways
// via LDS transpose.  Block: 64 spatial positions x 128 channels.
// ---------------------------------------------------------------------------
__global__ __launch_bounds__(256) void ln_cat_k(
    const float* __restrict__ pan, const float* __restrict__ ms,
    const float* __restrict__ lw, const float* __restrict__ lb,
    __hip_bfloat16* __restrict__ xb) {
  __shared__ float red[2][4][64];
  __shared__ ushort tile[64 * 130];
  int t = threadIdx.x;
  int i = t & 63, q = t >> 6;
  int blk = blockIdx.x;                  // 0..287 (72 per b)
  int b = blk / 72;
  int l0 = (blk % 72) * 64;
  const float* src = (l0 < HWc) ? pan : ms;
  int i0 = (l0 < HWc) ? l0 : l0 - HWc;
  const float* sb = src + (size_t)b * DIMc * HWc + i0 + i;
  float s = 0.f, ss = 0.f;
  #pragma unroll
  for (int cc = 0; cc < 32; ++cc) {
    float v = sb[(size_t)(q * 32 + cc) * HWc];
    s += v; ss += v * v;
  }
  red[0][q][i] = s; red[1][q][i] = ss;
  __syncthreads();
  float S  = red[0][0][i] + red[0][1][i] + red[0][2][i] + red[0][3][i];
  float SS = red[1][0][i] + red[1][1][i] + red[1][2][i] + red[1][3][i];
  float mean = S * (1.f / 128.f);
  float var  = SS * (1.f / 128.f) - mean * mean;
  float rstd = rsqrtf(var + 1e-5f);
  #pragma unroll
  for (int cc = 0; cc < 32; ++cc) {
    int c = q * 32 + cc;
    float v = sb[(size_t)c * HWc];
    float nv = (v - mean) * rstd * lw[c] + lb[c];
    __hip_bfloat16 bv = __float2bfloat16(nv);
    tile[i * 130 + c] = *reinterpret_cast<ushort*>(&bv);
  }
  __syncthreads();
  uint* dst = (uint*)xb + (size_t)blk * 64 * 64;   // 64 rows x 64 dwords
  #pragma unroll
  for (int it = 0; it < 16; ++it) {
    int idx = it * 256 + t;
    int row = idx >> 6, col2 = idx & 63;
    dst[idx] = *reinterpret_cast<uint*>(&tile[row * 130 + col2 * 2]);
  }
}

// ---------------------------------------------------------------------------
// bf16 MFMA GEMM, no LDS.  MODE 0: f32 out0 (ldc).  MODE 1: bf16 split at
// col 256 -> out0/out1 (both [*,256]).  MODE 2: col<256 softplus(v+bias)->
// bf16 out0; col>=256 f32 out1 [*,32].
// ---------------------------------------------------------------------------
template <int NF, int KK, int MODE>
__global__ __launch_bounds__(256) void gemm_mfma_k(
    const __hip_bfloat16* __restrict__ A, int lda,
    const __hip_bfloat16* __restrict__ Bw, int ldb,
    void* __restrict__ out0, void* __restrict__ out1,
    const float* __restrict__ bias, int ldc) {
  int lane = threadIdx.x & 63;
  int wv   = threadIdx.x >> 6;
  int m0 = blockIdx.x * 128 + wv * 32;
  int n0 = blockIdx.y * (NF * 16);
  int lm = lane & 15;
  int kb = lane >> 4;
  const short* Ap = (const short*)A + (size_t)(m0 + lm) * lda + kb * 8;
  const short* Bp = (const short*)Bw + (size_t)(n0 + lm) * ldb + kb * 8;
  float4v acc[2][NF] = {};
  for (int k0 = 0; k0 < KK; k0 += 32) {
    short8 a0 = *(const short8*)(Ap);
    short8 a1 = *(const short8*)(Ap + (size_t)16 * lda);
    short8 bfr[NF];
    #pragma unroll
    for (int j = 0; j < NF; ++j) bfr[j] = *(const short8*)(Bp + (size_t)j * 16 * ldb);
    #pragma unroll
    for (int j = 0; j < NF; ++j) {
      acc[0][j] = __builtin_amdgcn_mfma_f32_16x16x32_bf16(a0, bfr[j], acc[0][j], 0, 0, 0);
      acc[1][j] = __builtin_amdgcn_mfma_f32_16x16x32_bf16(a1, bfr[j], acc[1][j], 0, 0, 0);
    }
    Ap += 32; Bp += 32;
  }
  #pragma unroll
  for (int mf = 0; mf < 2; ++mf) {
    #pragma unroll
    for (int j = 0; j < NF; ++j) {
      int col = n0 + j * 16 + lm;
      #pragma unroll
      for (int r = 0; r < 4; ++r) {
        int row = m0 + mf * 16 + kb * 4 + r;
        float v = acc[mf][j][r];
        if (MODE == 0) {
          ((float*)out0)[(size_t)row * ldc + col] = v;
        } else if (MODE == 1) {
          if (col < 256)
            ((__hip_bfloat16*)out0)[(size_t)row * 256 + col] = __float2bfloat16(v);
          else
            ((__hip_bfloat16*)out1)[(size_t)row * 256 + col - 256] = __float2bfloat16(v);
        } else {
          if (col < 256) {
            float a2 = v + bias[col];
            float sp = (a2 > 20.f) ? a2 : log2_f(1.f + exp2_f(a2 * LOG2E)) * LN2;
            ((__hip_bfloat16*)out0)[(size_t)row * 256 + col] = __float2bfloat16(sp);
          } else {
            ((float*)out1)[(size_t)row * 32 + col - 256] = v;
          }
        }
      }
    }
  }
}

// ---------------------------------------------------------------------------
// K3: causal depthwise conv1d (taps=4) + SiLU, sliding window, 64 rows/block.
// ---------------------------------------------------------------------------
__global__ __launch_bounds__(256) void conv_silu_k(
    const __hip_bfloat16* __restrict__ xsr, const float* __restrict__ cw,
    const float* __restrict__ cb, __hip_bfloat16* __restrict__ xsb) {
  int d = threadIdx.x;
  int blk = blockIdx.x;                  // 0..287 (72 per b)
  int b = blk / 72, l0 = (blk % 72) * 64;
  const __hip_bfloat16* base = xsr + (size_t)b * Ltot * 256 + d;
  float w0 = cw[d * 4], w1 = cw[d * 4 + 1], w2 = cw[d * 4 + 2], w3 = cw[d * 4 + 3];
  float bia = cb[d];
  float h0 = (l0 >= 3) ? __bfloat162float(base[(size_t)(l0 - 3) * 256]) : 0.f;
  float h1 = (l0 >= 2) ? __bfloat162float(base[(size_t)(l0 - 2) * 256]) : 0.f;
  float h2 = (l0 >= 1) ? __bfloat162float(base[(size_t)(l0 - 1) * 256]) : 0.f;
  __hip_bfloat16* op = xsb + ((size_t)b * Ltot + l0) * 256 + d;
  for (int u = 0; u < 64; ++u) {
    float cur = __bfloat162float(base[(size_t)(l0 + u) * 256]);
    float acc = fmaf(w0, h0, bia);
    acc = fmaf(w1, h1, acc);
    acc = fmaf(w2, h2, acc);
    acc = fmaf(w3, cur, acc);
    float sig = rcp_f(1.f + exp2_f(-acc * LOG2E));
    op[(size_t)u * 256] = __float2bfloat16(acc * sig);
    h0 = h1; h1 = h2; h2 = cur;
  }
}

// ---------------------------------------------------------------------------
// Chunk-parallel scan, layout B (1 lane = 1 channel, 16 states in VGPRs).
// ---------------------------------------------------------------------------
__global__ __launch_bounds__(256, 2) void scan_p1_k(
    const __hip_bfloat16* __restrict__ dlt, const __hip_bfloat16* __restrict__ xsb,
    const float* __restrict__ dbc, const float* __restrict__ A_log,
    float* __restrict__ Pb, float* __restrict__ Sb) {
  constexpr int LCH = Ltot / NC;         // 36
  __shared__ float4 BCs[LCH * 8];
  int tid = threadIdx.x;
  int c = blockIdx.x, b = blockIdx.y;
  size_t rb = (size_t)b * Ltot + (size_t)c * LCH;
  float* BCf = (float*)BCs;
  for (int i = tid; i < LCH * 32; i += 256) BCf[i] = dbc[rb * 32 + i];
  __syncthreads();
  int d = tid;
  const float4* Ap = (const float4*)(A_log + d * 16);
  float An2[16];
  #pragma unroll
  for (int k = 0; k < 4; ++k) {
    float4 a4 = Ap[k];
    An2[4 * k + 0] = -exp2_f(a4.x * LOG2E) * LOG2E;
    An2[4 * k + 1] = -exp2_f(a4.y * LOG2E) * LOG2E;
    An2[4 * k + 2] = -exp2_f(a4.z * LOG2E) * LOG2E;
    An2[4 * k + 3] = -exp2_f(a4.w * LOG2E) * LOG2E;
  }
  float h[16];
  #pragma unroll
  for (int n = 0; n < 16; ++n) h[n] = 0.f;
  float sdlt = 0.f;
  const __hip_bfloat16* dp = dlt + rb * 256 + d;
  const __hip_bfloat16* xp = xsb + rb * 256 + d;
  for (int ss = 0; ss < LCH / 4; ++ss) {
    float dv[4], xv[4];
    #pragma unroll
    for (int u = 0; u < 4; ++u) {
      dv[u] = __bfloat162float(dp[(size_t)u * 256]);
      xv[u] = __bfloat162float(xp[(size_t)u * 256]);
    }
    #pragma unroll
    for (int u = 0; u < 4; ++u) {
      int l = ss * 4 + u;
      float dl = dv[u];
      sdlt += dl;
      float q = dl * xv[u];
      const float4* row = &BCs[l * 8];
      float4 B4[4] = {row[0], row[1], row[2], row[3]};
      #pragma unroll
      for (int n = 0; n < 16; ++n) {
        float a = exp2_f(dl * An2[n]);
        h[n] = fmaf(a, h[n], q * F4C(B4[n >> 2], n & 3));
      }
    }
    dp += 1024; xp += 1024;
  }
  size_t s0 = ((size_t)b * 256 + d) * 16;
  float4* Pp = (float4*)(Pb + (size_t)c * LANES + s0);
  float4* Sp = (float4*)(Sb + (size_t)c * LANES + s0);
  #pragma unroll
  for (int k = 0; k < 4; ++k) {
    float4 Pq, Sq;
    Pq.x = exp2_f(An2[4 * k + 0] * sdlt);
    Pq.y = exp2_f(An2[4 * k + 1] * sdlt);
    Pq.z = exp2_f(An2[4 * k + 2] * sdlt);
    Pq.w = exp2_f(An2[4 * k + 3] * sdlt);
    Sq.x = h[4 * k + 0]; Sq.y = h[4 * k + 1];
    Sq.z = h[4 * k + 2]; Sq.w = h[4 * k + 3];
    Pp[k] = Pq; Sp[k] = Sq;
  }
}

// p2: exclusive prefix combine; batch-prefetch 8 chunks (16 loads in flight).
// 64-thread blocks on 256 blocks -> all CUs.  Hin written in place into Pb.
__global__ __launch_bounds__(64) void scan_p2_k(
    float* __restrict__ Pb, const float* __restrict__ Sb) {
  int s = blockIdx.x * 64 + threadIdx.x;
  float h = 0.f;
  for (int cb = 0; cb < NC / 8; ++cb) {
    float Pv[8], Sv[8];
    #pragma unroll
    for (int u = 0; u < 8; ++u) {
      size_t i = (size_t)(cb * 8 + u) * LANES + s;
      Pv[u] = Pb[i]; Sv[u] = Sb[i];
    }
    #pragma unroll
    for (int u = 0; u < 8; ++u) {
      Pb[(size_t)(cb * 8 + u) * LANES + s] = h;
      h = fmaf(Pv[u], h, Sv[u]);
    }
  }
}

__global__ __launch_bounds__(256, 2) void scan_p3_k(
    const __hip_bfloat16* __restrict__ dlt, const __hip_bfloat16* __restrict__ xsb,
    const float* __restrict__ dbc, const float* __restrict__ A_log,
    const float* __restrict__ Dp, const float* __restrict__ Hin,
    const __hip_bfloat16* __restrict__ zb, __hip_bfloat16* __restrict__ y) {
  constexpr int LCH = Ltot / NC;
  __shared__ float4 BCs[LCH * 8];
  int tid = threadIdx.x;
  int c = blockIdx.x, b = blockIdx.y;
  size_t rb = (size_t)b * Ltot + (size_t)c * LCH;
  float* BCf = (float*)BCs;
  for (int i = tid; i < LCH * 32; i += 256) BCf[i] = dbc[rb * 32 + i];
  __syncthreads();
  int d = tid;
  const float4* Ap = (const float4*)(A_log + d * 16);
  float An2[16];
  #pragma unroll
  for (int k = 0; k < 4; ++k) {
    float4 a4 = Ap[k];
    An2[4 * k + 0] = -exp2_f(a4.x * LOG2E) * LOG2E;
    An2[4 * k + 1] = -exp2_f(a4.y * LOG2E) * LOG2E;
    An2[4 * k + 2] = -exp2_f(a4.z * LOG2E) * LOG2E;
    An2[4 * k + 3] = -exp2_f(a4.w * LOG2E) * LOG2E;
  }
  float Dd = Dp[d];
  size_t s0 = ((size_t)b * 256 + d) * 16;
  const float4* Hp = (const float4*)(Hin + (size_t)c * LANES + s0);
  float h[16];
  #pragma unroll
  for (int k = 0; k < 4; ++k) {
    float4 h4 = Hp[k];
    h[4 * k + 0] = h4.x; h[4 * k + 1] = h4.y;
    h[4 * k + 2] = h4.z; h[4 * k + 3] = h4.w;
  }
  const __hip_bfloat16* dp = dlt + rb * 256 + d;
  const __hip_bfloat16* xp = xsb + rb * 256 + d;
  const __hip_bfloat16* zp = zb + rb * 256 + d;
  __hip_bfloat16* yp = y + rb * 256 + d;
  for (int ss = 0; ss < LCH / 4; ++ss) {
    float dv[4], xv[4], zv[4];
    #pragma unroll
    for (int u = 0; u < 4; ++u) {
      dv[u] = __bfloat162float(dp[(size_t)u * 256]);
      xv[u] = __bfloat162float(xp[(size_t)u * 256]);
      zv[u] = __bfloat162float(zp[(size_t)u * 256]);
    }
    #pragma unroll
    for (int u = 0; u < 4; ++u) {
      int l = ss * 4 + u;
      float dl = dv[u];
      float q = dl * xv[u];
      const float4* row = &BCs[l * 8];
      float4 B4[4] = {row[0], row[1], row[2], row[3]};
      float4 C4[4] = {row[4], row[5], row[6], row[7]};
      float p0 = 0.f, p1 = 0.f, p2 = 0.f, p3 = 0.f;
      #pragma unroll
      for (int n = 0; n < 16; ++n) {
        float a = exp2_f(dl * An2[n]);
        h[n] = fmaf(a, h[n], q * F4C(B4[n >> 2], n & 3));
        float cc = F4C(C4[n >> 2], n & 3);
        if ((n & 3) == 0)      p0 = fmaf(h[n], cc, p0);
        else if ((n & 3) == 1) p1 = fmaf(h[n], cc, p1);
        else if ((n & 3) == 2) p2 = fmaf(h[n], cc, p2);
        else                   p3 = fmaf(h[n], cc, p3);
      }
      float p = (p0 + p1) + (p2 + p3);
      float zc = zv[u];
      float sig = rcp_f(1.f + exp2_f(-zc * LOG2E));
      yp[(size_t)u * 256] = __float2bfloat16(fmaf(xv[u], Dd, p) * (zc * sig));
    }
    dp += 1024; xp += 1024; zp += 1024; yp += 1024;
  }
}

// ---------------------------------------------------------------------------
// K8: out = pan + ms + fused[b,i,:] + fused[b,hw+i,:] ; LDS transpose.
// Block: 64 positions x 128 channels; grid (36, Bc).
// ---------------------------------------------------------------------------
__global__ __launch_bounds__(256) void final_k(
    const float* __restrict__ pan, const float* __restrict__ ms,
    const float* __restrict__ fused, float* __restrict__ out) {
  __shared__ float tile[64 * 129];
  int t = threadIdx.x;
  int i0 = blockIdx.x * 64;
  int b  = blockIdx.y;
  int c = t & 127, rh = t >> 7;
  const float* f0 = fused + ((size_t)b * Ltot + i0) * 128 + c;
  const float* f1 = fused + ((size_t)b * Ltot + HWc + i0) * 128 + c;
  for (int rr = 0; rr < 32; ++rr) {
    int ri = rh * 32 + rr;
    tile[ri * 129 + c] = f0[(size_t)ri * 128] + f1[(size_t)ri * 128];
  }
  __syncthreads();
  #pragma unroll
  for (int it = 0; it < 32; ++it) {
    int lin = it * 256 + t;               // 128 c x 64 i
    int cc = lin >> 6, ii = lin & 63;
    size_t gi = ((size_t)b * DIMc + cc) * HWc + i0 + ii;
    out[gi] = pan[gi] + ms[gi] + tile[ii * 129 + cc];
  }
}

// ---------------------------------------------------------------------------
extern "C" void kernel_launch(void* const* d_in, const int* in_sizes, int n_in,
                              void* d_out, int out_size, void* d_ws, size_t ws_size,
                              hipStream_t stream) {
  const float* pan   = (const float*)d_in[0];
  const float* ms    = (const float*)d_in[1];
  const float* ln_w  = (const float*)d_in[2];
  const float* ln_b  = (const float*)d_in[3];
  const float* inW   = (const float*)d_in[4];
  const float* convw = (const float*)d_in[5];
  const float* convb = (const float*)d_in[6];
  const float* xprW  = (const float*)d_in[7];
  const float* dtW   = (const float*)d_in[8];
  const float* dtb   = (const float*)d_in[9];
  const float* A_log = (const float*)d_in[10];
  const float* Dp    = (const float*)d_in[11];
  const float* outW  = (const float*)d_in[12];
  float* out = (float*)d_out;

  float* p = (float*)d_ws;
  __hip_bfloat16* xb    = (__hip_bfloat16*)p; p += (size_t)ROWS * 64;
  __hip_bfloat16* xsr   = (__hip_bfloat16*)p; p += (size_t)ROWS * 128;
  __hip_bfloat16* zb    = (__hip_bfloat16*)p; p += (size_t)ROWS * 128;
  __hip_bfloat16* xsb   = (__hip_bfloat16*)p; p += (size_t)ROWS * 128;
  __hip_bfloat16* dlt   = (__hip_bfloat16*)p; p += (size_t)ROWS * 128;
  float*          dbc   = p;                  p += (size_t)ROWS * 32;
  __hip_bfloat16* y     = (__hip_bfloat16*)p; p += (size_t)ROWS * 128;
  float*          fused = p;                  p += (size_t)ROWS * 128;
  float*          Pb    = p;                  p += (size_t)NC * LANES;
  float*          Sb    = p;                  p += (size_t)NC * LANES;
  __hip_bfloat16* wts   = (__hip_bfloat16*)p;
  __hip_bfloat16* wq    = wts;            // 65536 (Wcomb, then BCw adjacent)
  __hip_bfloat16* inWb  = wts + 73728;    // 65536
  __hip_bfloat16* outWb = wts + 139264;   // 32768

  // K0: weight prep
  prep_w_k<<<672, 256, 0, stream>>>(inW, xprW, dtW, outW, wts);
  // K1: layernorm -> xb bf16
  ln_cat_k<<<288, 256, 0, stream>>>(pan, ms, ln_w, ln_b, xb);
  // K2: in_proj: xb[ROWS,128] @ inWb[512,128]^T -> xsr bf16 | zb bf16
  gemm_mfma_k<4, 128, 1><<<dim3(ROWS / 128, 8), 256, 0, stream>>>(
      xb, 128, inWb, 128, xsr, zb, nullptr, 0);
  // K3: conv + silu -> xsb bf16
  conv_silu_k<<<288, 256, 0, stream>>>(xsr, convw, convb, xsb);
  // K4: x_proj+delta: xsb @ [Wq;BCw][288,256]^T -> dlt bf16 (softplus) | dbc f32
  gemm_mfma_k<6, 256, 2><<<dim3(ROWS / 128, 3), 256, 0, stream>>>(
      xsb, 256, wq, 256, dlt, dbc, dtb, 0);
  // K6: chunk-parallel scan
  scan_p1_k<<<dim3(NC, Bc), 256, 0, stream>>>(dlt, xsb, dbc, A_log, Pb, Sb);
  scan_p2_k<<<LANES / 64, 64, 0, stream>>>(Pb, Sb);
  scan_p3_k<<<dim3(NC, Bc), 256, 0, stream>>>(dlt, xsb, dbc, A_log, Dp, Pb, zb, y);
  // K7: out_proj: y[ROWS,256] @ outWb[128,256]^T -> fused f32
  gemm_mfma_k<4, 256, 0><<<dim3(ROWS / 128, 2), 256, 0, stream>>>(
      y, 256, outWb, 256, fused, nullptr, nullptr, 128);
  // K8: residual + fold p+m (transposed, coalesced)
  final_k<<<dim3(HWc / 64, Bc), 256, 0, stream>>>(pan, ms, fused, out);
}